// Round 7
// baseline (492.717 us; speedup 1.0000x reference)
//
#include <hip/hip_runtime.h>
#include <hip/hip_bf16.h>
#include <math.h>

// Problem constants
#define C_DIM 256
#define BD    128   // B*D
#define HW    784   // H*W = K
#define CN    128
#define KPAD  832   // 26 k-tiles of 32; rows = 1664 B = 13 x 128 B (line-aligned)
#define KTILES 26

typedef short bf16x8 __attribute__((ext_vector_type(8)));
typedef float f32x4 __attribute__((ext_vector_type(4)));

// fp32 -> bf16 RNE
__device__ inline ushort f2b(float f) {
  unsigned u = __float_as_uint(f);
  unsigned r = (u + 0x7FFFu + ((u >> 16) & 1u)) >> 16;
  return (ushort)r;
}

// ---------------------------------------------------------------------------
// K1: LayerNorm over C + transpose -> bf16 x_re [C][BD][KPAD] + row norms.
// grid (13, 128), block 256. Quad-row: each 16-lane quad owns one hw row,
// parallel sum/sumsq 4-step quad shuffle. hw-tile 64 (block 12: 16 rows +
// 48 zero-pad). LDS [c][64] ushort, column-swizzled r' = r ^ ((c>>2)&12).
// Write-out: uint2/lane -> 128 B line-aligned per channel (KPAD=832).
// ---------------------------------------------------------------------------
__global__ __launch_bounds__(256) void ln_transpose_kernel(
    const float* __restrict__ x, const float* __restrict__ lnw,
    const float* __restrict__ lnb, ushort* __restrict__ xre,
    float* __restrict__ anorm) {
  __shared__ ushort btile[256 * 64];   // 32 KB, swizzled columns
  __shared__ float nbuf[4][256];
  const int t = threadIdx.x, bd = blockIdx.y, bx = blockIdx.x;
  const int hw0 = bx * 64;
  const int w = t >> 6, lane = t & 63;
  const int q = lane >> 4, l = lane & 15;
  const bool last = (bx == 12);
  const int ngroups = last ? 1 : 4;
  const int rpw = ngroups * 4;
  if (last) {  // zero rows 16..63 (hw 784..831); swizzle region is closed
    for (int r = 16; r < 64; r += 4)
      *(ushort4*)&btile[t * 64 + r] = make_ushort4(0, 0, 0, 0);
  }
  float4 wv[4], bv[4];
  for (int s = 0; s < 4; ++s) {
    wv[s] = *(const float4*)(lnw + s * 64 + l * 4);
    bv[s] = *(const float4*)(lnb + s * 64 + l * 4);
  }
  float nrm[4][4];
  for (int s = 0; s < 4; ++s)
    for (int j = 0; j < 4; ++j) nrm[s][j] = 0.f;
  const float* xb = x + ((size_t)bd * HW + hw0) * 256 + l * 4;
  const int xr = l & 12;               // (c>>2)&12 for c = s*64 + l*4 + j
  for (int g = 0; g < ngroups; ++g) {
    int r = w * rpw + g * 4 + q;       // block-local row
    float4 v[4];
    for (int s = 0; s < 4; ++s)
      v[s] = *(const float4*)(xb + (size_t)r * 256 + s * 64);
    float sum = 0.f, sq = 0.f;
    for (int s = 0; s < 4; ++s) {
      sum += v[s].x + v[s].y + v[s].z + v[s].w;
      sq = fmaf(v[s].x, v[s].x, sq); sq = fmaf(v[s].y, v[s].y, sq);
      sq = fmaf(v[s].z, v[s].z, sq); sq = fmaf(v[s].w, v[s].w, sq);
    }
    for (int off = 1; off <= 8; off <<= 1) {
      sum += __shfl_xor(sum, off, 64);
      sq  += __shfl_xor(sq, off, 64);
    }
    float mu = sum * (1.f / 256.f);
    float var = fmaf(-mu, mu, sq * (1.f / 256.f));
    float sc = rsqrtf(var + 1e-5f);
    int rp = r ^ xr;
    for (int s = 0; s < 4; ++s) {
      float y0 = (v[s].x - mu) * sc * wv[s].x + bv[s].x;
      float y1 = (v[s].y - mu) * sc * wv[s].y + bv[s].y;
      float y2 = (v[s].z - mu) * sc * wv[s].z + bv[s].z;
      float y3 = (v[s].w - mu) * sc * wv[s].w + bv[s].w;
      nrm[s][0] = fmaf(y0, y0, nrm[s][0]);
      nrm[s][1] = fmaf(y1, y1, nrm[s][1]);
      nrm[s][2] = fmaf(y2, y2, nrm[s][2]);
      nrm[s][3] = fmaf(y3, y3, nrm[s][3]);
      int c = s * 64 + l * 4;
      btile[(c + 0) * 64 + rp] = f2b(y0);
      btile[(c + 1) * 64 + rp] = f2b(y1);
      btile[(c + 2) * 64 + rp] = f2b(y2);
      btile[(c + 3) * 64 + rp] = f2b(y3);
    }
  }
  // reduce norms over the 4 quads, q==0 publishes
  for (int s = 0; s < 4; ++s)
    for (int j = 0; j < 4; ++j) {
      float v = nrm[s][j];
      v += __shfl_xor(v, 16, 64);
      v += __shfl_xor(v, 32, 64);
      nrm[s][j] = v;
    }
  if (q == 0)
    for (int s = 0; s < 4; ++s)
      for (int j = 0; j < 4; ++j) nbuf[w][s * 64 + l * 4 + j] = nrm[s][j];
  __syncthreads();
  float tot = nbuf[0][t] + nbuf[1][t] + nbuf[2][t] + nbuf[3][t];
  atomicAdd(&anorm[t * 128 + bd], tot);  // anorm[c][bd]
  // write-out: uint2/lane; 4 channels x 128 B aligned per instruction
  for (int i = 0; i < 16; ++i) {
    int c = w * 64 + i * 4 + (lane >> 4);
    int xw = (w * 16 + i) & 12;          // (c>>2)&12
    int ho = (lane & 15) * 4;
    uint2 val = *(const uint2*)&btile[c * 64 + (ho ^ xw)];
    *(uint2*)(xre + (size_t)c * (BD * KPAD) + (size_t)bd * KPAD + hw0 + ho) = val;
  }
}

// ---------------------------------------------------------------------------
// K2: cc fp32 -> bf16 [C][CN][KPAD] + fp32 row norms + zero K-pad.
// grid 2048, block 256. Quad-row; 4-step quad shuffle for the norm.
// ---------------------------------------------------------------------------
__global__ __launch_bounds__(256) void cc_convert_kernel(
    const float* __restrict__ cc, ushort* __restrict__ ccb,
    float* __restrict__ bnorm) {
  int b = blockIdx.x, c = b >> 3;
  int t = threadIdx.x, w = t >> 6, lane = t & 63;
  int q = lane >> 4, l = lane & 15;
  int r = (b & 7) * 16 + w * 4 + q;
  const float4* src = (const float4*)(cc + ((size_t)c * CN + r) * HW);
  ushort* dst = ccb + ((size_t)c * CN + r) * KPAD;
  float nrm = 0.f;
  for (int i = 0; i < 13; ++i) {
    int f = i * 16 + l;
    if (f < 196) {
      float4 v = src[f];
      nrm = fmaf(v.x, v.x, nrm); nrm = fmaf(v.y, v.y, nrm);
      nrm = fmaf(v.z, v.z, nrm); nrm = fmaf(v.w, v.w, nrm);
      ushort4 o; o.x = f2b(v.x); o.y = f2b(v.y); o.z = f2b(v.z); o.w = f2b(v.w);
      *(ushort4*)(dst + f * 4) = o;
    }
  }
  for (int off = 1; off <= 8; off <<= 1) nrm += __shfl_xor(nrm, off, 64);
  if (l == 0) bnorm[c * 128 + r] = nrm;
  if (l < 12) *(ushort4*)(dst + 784 + l * 4) = make_ushort4(0, 0, 0, 0);  // 784..831
}

// ---------------------------------------------------------------------------
// K3: fused MFMA GEMM-dist. grid 256 (one block per c), 512 threads (8 waves).
// Stage xre[c] (At) and ccb[c] (Bt) k-tiles ONCE; compute
//   D_x = A.B^T (dist + in-register softmax)  and  D_c = B.B^T
// from the same staged tiles. Wave w owns rows w*16..+15 of both outputs,
// all 128 cols in registers. bf[w] doubles as the A-operand for D_c.
// Double-buffered, issue-after-barrier. XOR chunk swizzle as before.
// ---------------------------------------------------------------------------
__global__ __launch_bounds__(512) void gemm_fused_kernel(
    const ushort* __restrict__ xre, const ushort* __restrict__ ccb,
    const float* __restrict__ anorm, const float* __restrict__ bnorm,
    float* __restrict__ out_d, float* __restrict__ out_s,
    float* __restrict__ out_c) {
  __shared__ __align__(16) ushort At[2][4096];  // 128 rows x 32 k
  __shared__ __align__(16) ushort Bt[2][4096];
  const int c = blockIdx.x;
  const int t = threadIdx.x, w = t >> 6, lane = t & 63;
  const int quad = lane >> 4, ln = lane & 15;
  const ushort* Ag = xre + (size_t)c * (128 * KPAD);
  const ushort* Bg = ccb + (size_t)c * (128 * KPAD);

  f32x4 accx[8], accc[8];
  for (int j = 0; j < 8; ++j) {
    accx[j] = f32x4{0.f, 0.f, 0.f, 0.f};
    accc[j] = f32x4{0.f, 0.f, 0.f, 0.f};
  }

  // staging: thread t covers chunk ci = t of the 128x32 tile
  // (row = ci>>2, stored chunk index q = (ci&3)^(row&3))
  const int srow = t >> 2, scq = (t & 3) ^ (srow & 3);
  const ushort* gA = Ag + (size_t)srow * KPAD + scq * 8;
  const ushort* gB = Bg + (size_t)srow * KPAD + scq * 8;

#define ISSUE(k, p)                                                            \
  do {                                                                         \
    int kb = (k) * 32;                                                         \
    __builtin_amdgcn_global_load_lds(                                          \
        (const __attribute__((address_space(1))) unsigned int*)(gA + kb),      \
        (__attribute__((address_space(3))) unsigned int*)&At[p][t * 8], 16, 0, 0); \
    __builtin_amdgcn_global_load_lds(                                          \
        (const __attribute__((address_space(1))) unsigned int*)(gB + kb),      \
        (__attribute__((address_space(3))) unsigned int*)&Bt[p][t * 8], 16, 0, 0); \
  } while (0)

  ISSUE(0, 0);
  for (int k0 = 0; k0 < KTILES; ++k0) {
    __syncthreads();
    if (k0 < KTILES - 1) ISSUE(k0 + 1, (k0 + 1) & 1);
    const int p = k0 & 1;
    const int m = w * 16 + ln;
    bf16x8 af = *(const bf16x8*)&At[p][(m * 4 + (quad ^ (m & 3))) * 8];
    bf16x8 bf[8];
    for (int j = 0; j < 8; ++j) {
      int n = j * 16 + ln;
      bf[j] = *(const bf16x8*)&Bt[p][(n * 4 + (quad ^ (n & 3))) * 8];
    }
    bf16x8 ar = bf[w];   // B-rows w*16.. as A-operand for D_c
    for (int j = 0; j < 8; ++j) {
      accx[j] = __builtin_amdgcn_mfma_f32_16x16x32_bf16(af, bf[j], accx[j], 0, 0, 0);
      accc[j] = __builtin_amdgcn_mfma_f32_16x16x32_bf16(ar, bf[j], accc[j], 0, 0, 0);
    }
  }
#undef ISSUE

  const float* an = anorm + c * 128;
  const float* bn = bnorm + c * 128;
  float cn[8];
  for (int j = 0; j < 8; ++j) cn[j] = bn[j * 16 + ln];
  float rx[4], rc[4];
  for (int r = 0; r < 4; ++r) {
    int m = w * 16 + quad * 4 + r;
    rx[r] = an[m];
    rc[r] = bn[m];
  }
  // cluster_dist
  for (int r = 0; r < 4; ++r) {
    int m = w * 16 + quad * 4 + r;
    float* ob = out_c + (size_t)c * (128 * 128) + (size_t)m * 128;
    for (int j = 0; j < 8; ++j) {
      float d2 = rc[r] + cn[j] - 2.f * accc[j][r];
      ob[j * 16 + ln] = sqrtf(fmaxf(d2, 1e-12f));
    }
  }
  // x_distance + softmax (row fully in-wave: 8 regs x 16 ln within a quad)
  for (int r = 0; r < 4; ++r) {
    int m = w * 16 + quad * 4 + r;
    float dr[8];
    for (int j = 0; j < 8; ++j) {
      float d2 = rx[r] + cn[j] - 2.f * accx[j][r];
      dr[j] = sqrtf(fmaxf(d2, 1e-12f));
    }
    float* ob = out_d + ((size_t)m * 256 + c) * 128;
    for (int j = 0; j < 8; ++j) ob[j * 16 + ln] = dr[j];
    float mn = dr[0];
    for (int j = 1; j < 8; ++j) mn = fminf(mn, dr[j]);
    for (int off = 1; off <= 8; off <<= 1) mn = fminf(mn, __shfl_xor(mn, off, 64));
    float e[8], s = 0.f;
    for (int j = 0; j < 8; ++j) { e[j] = __expf(-32.f * (dr[j] - mn)); s += e[j]; }
    for (int off = 1; off <= 8; off <<= 1) s += __shfl_xor(s, off, 64);
    float inv = 1.f / s;
    float* os = out_s + ((size_t)m * 256 + c) * 128;
    for (int j = 0; j < 8; ++j) os[j * 16 + ln] = e[j] * inv;
  }
}

extern "C" void kernel_launch(void* const* d_in, const int* in_sizes, int n_in,
                              void* d_out, int out_size, void* d_ws, size_t ws_size,
                              hipStream_t stream) {
  const float* x   = (const float*)d_in[0];
  const float* lnw = (const float*)d_in[1];
  const float* lnb = (const float*)d_in[2];
  const float* cc  = (const float*)d_in[3];
  float* out   = (float*)d_out;
  float* out_d = out;             // x_distance        [8,16,256,128]
  float* out_s = out + 4194304;   // x_distance_assign [8,16,256,128]
  float* out_c = out + 8388608;   // cluster_dist      [256,128,128]

  ushort* xre_b = (ushort*)d_ws;              // 256*128*832 bf16 = 54.5 MB
  ushort* cc_b  = xre_b + 27262976;           // 54.5 MB
  float*  anorm = (float*)(cc_b + 27262976);  // 256*128 fp32
  float*  bnorm = anorm + 32768;

  hipMemsetAsync(anorm, 0, 32768 * sizeof(float), stream);
  ln_transpose_kernel<<<dim3(13, 128), 256, 0, stream>>>(x, lnw, lnb, xre_b, anorm);
  cc_convert_kernel<<<2048, 256, 0, stream>>>(cc, cc_b, bnorm);
  gemm_fused_kernel<<<256, 512, 0, stream>>>(xre_b, cc_b, anorm, bnorm,
                                             out_d, out_s, out_c);
}

// Round 8
// 295.641 us; speedup vs baseline: 1.6666x; 1.6666x over previous
//
#include <hip/hip_runtime.h>
#include <hip/hip_bf16.h>
#include <math.h>

// Problem constants
#define C_DIM 256
#define BD    128   // B*D
#define HW    784   // H*W = K
#define CN    128
#define KPAD  832   // 26 k-tiles of 32; rows = 1664 B = 13 x 128 B (line-aligned)
#define KTILES 26

typedef short bf16x8 __attribute__((ext_vector_type(8)));
typedef float f32x4 __attribute__((ext_vector_type(4)));

// fp32 -> bf16 RNE
__device__ inline ushort f2b(float f) {
  unsigned u = __float_as_uint(f);
  unsigned r = (u + 0x7FFFu + ((u >> 16) & 1u)) >> 16;
  return (ushort)r;
}

// ---------------------------------------------------------------------------
// K1: LayerNorm over C + transpose -> bf16 x_re [C][BD][KPAD] + row norms.
// grid (13, 128), block 256. Quad-row: each 16-lane quad owns one hw row,
// parallel sum/sumsq 4-step quad shuffle. hw-tile 64 (block 12: 16 rows +
// 48 zero-pad). LDS [c][64] ushort, column-swizzled r' = r ^ ((c>>2)&12).
// Write-out: uint2/lane -> 128 B line-aligned per channel (KPAD=832).
// ---------------------------------------------------------------------------
__global__ __launch_bounds__(256) void ln_transpose_kernel(
    const float* __restrict__ x, const float* __restrict__ lnw,
    const float* __restrict__ lnb, ushort* __restrict__ xre,
    float* __restrict__ anorm) {
  __shared__ ushort btile[256 * 64];   // 32 KB, swizzled columns
  __shared__ float nbuf[4][256];
  const int t = threadIdx.x, bd = blockIdx.y, bx = blockIdx.x;
  const int hw0 = bx * 64;
  const int w = t >> 6, lane = t & 63;
  const int q = lane >> 4, l = lane & 15;
  const bool last = (bx == 12);
  const int ngroups = last ? 1 : 4;
  const int rpw = ngroups * 4;
  if (last) {  // zero rows 16..63 (hw 784..831); swizzle region is closed
    for (int r = 16; r < 64; r += 4)
      *(ushort4*)&btile[t * 64 + r] = make_ushort4(0, 0, 0, 0);
  }
  float4 wv[4], bv[4];
  for (int s = 0; s < 4; ++s) {
    wv[s] = *(const float4*)(lnw + s * 64 + l * 4);
    bv[s] = *(const float4*)(lnb + s * 64 + l * 4);
  }
  float nrm[4][4];
  for (int s = 0; s < 4; ++s)
    for (int j = 0; j < 4; ++j) nrm[s][j] = 0.f;
  const float* xb = x + ((size_t)bd * HW + hw0) * 256 + l * 4;
  const int xr = l & 12;               // (c>>2)&12 for c = s*64 + l*4 + j
  for (int g = 0; g < ngroups; ++g) {
    int r = w * rpw + g * 4 + q;       // block-local row
    float4 v[4];
    for (int s = 0; s < 4; ++s)
      v[s] = *(const float4*)(xb + (size_t)r * 256 + s * 64);
    float sum = 0.f, sq = 0.f;
    for (int s = 0; s < 4; ++s) {
      sum += v[s].x + v[s].y + v[s].z + v[s].w;
      sq = fmaf(v[s].x, v[s].x, sq); sq = fmaf(v[s].y, v[s].y, sq);
      sq = fmaf(v[s].z, v[s].z, sq); sq = fmaf(v[s].w, v[s].w, sq);
    }
    for (int off = 1; off <= 8; off <<= 1) {
      sum += __shfl_xor(sum, off, 64);
      sq  += __shfl_xor(sq, off, 64);
    }
    float mu = sum * (1.f / 256.f);
    float var = fmaf(-mu, mu, sq * (1.f / 256.f));
    float sc = rsqrtf(var + 1e-5f);
    int rp = r ^ xr;
    for (int s = 0; s < 4; ++s) {
      float y0 = (v[s].x - mu) * sc * wv[s].x + bv[s].x;
      float y1 = (v[s].y - mu) * sc * wv[s].y + bv[s].y;
      float y2 = (v[s].z - mu) * sc * wv[s].z + bv[s].z;
      float y3 = (v[s].w - mu) * sc * wv[s].w + bv[s].w;
      nrm[s][0] = fmaf(y0, y0, nrm[s][0]);
      nrm[s][1] = fmaf(y1, y1, nrm[s][1]);
      nrm[s][2] = fmaf(y2, y2, nrm[s][2]);
      nrm[s][3] = fmaf(y3, y3, nrm[s][3]);
      int c = s * 64 + l * 4;
      btile[(c + 0) * 64 + rp] = f2b(y0);
      btile[(c + 1) * 64 + rp] = f2b(y1);
      btile[(c + 2) * 64 + rp] = f2b(y2);
      btile[(c + 3) * 64 + rp] = f2b(y3);
    }
  }
  // reduce norms over the 4 quads, q==0 publishes
  for (int s = 0; s < 4; ++s)
    for (int j = 0; j < 4; ++j) {
      float v = nrm[s][j];
      v += __shfl_xor(v, 16, 64);
      v += __shfl_xor(v, 32, 64);
      nrm[s][j] = v;
    }
  if (q == 0)
    for (int s = 0; s < 4; ++s)
      for (int j = 0; j < 4; ++j) nbuf[w][s * 64 + l * 4 + j] = nrm[s][j];
  __syncthreads();
  float tot = nbuf[0][t] + nbuf[1][t] + nbuf[2][t] + nbuf[3][t];
  atomicAdd(&anorm[t * 128 + bd], tot);  // anorm[c][bd]
  // write-out: uint2/lane; 4 channels x 128 B aligned per instruction
  for (int i = 0; i < 16; ++i) {
    int c = w * 64 + i * 4 + (lane >> 4);
    int xw = (w * 16 + i) & 12;          // (c>>2)&12
    int ho = (lane & 15) * 4;
    uint2 val = *(const uint2*)&btile[c * 64 + (ho ^ xw)];
    *(uint2*)(xre + (size_t)c * (BD * KPAD) + (size_t)bd * KPAD + hw0 + ho) = val;
  }
}

// ---------------------------------------------------------------------------
// K2: cc fp32 -> bf16 [C][CN][KPAD] + fp32 row norms + zero K-pad.
// grid 2048, block 256. Quad-row; 4-step quad shuffle for the norm.
// ---------------------------------------------------------------------------
__global__ __launch_bounds__(256) void cc_convert_kernel(
    const float* __restrict__ cc, ushort* __restrict__ ccb,
    float* __restrict__ bnorm) {
  int b = blockIdx.x, c = b >> 3;
  int t = threadIdx.x, w = t >> 6, lane = t & 63;
  int q = lane >> 4, l = lane & 15;
  int r = (b & 7) * 16 + w * 4 + q;
  const float4* src = (const float4*)(cc + ((size_t)c * CN + r) * HW);
  ushort* dst = ccb + ((size_t)c * CN + r) * KPAD;
  float nrm = 0.f;
  for (int i = 0; i < 13; ++i) {
    int f = i * 16 + l;
    if (f < 196) {
      float4 v = src[f];
      nrm = fmaf(v.x, v.x, nrm); nrm = fmaf(v.y, v.y, nrm);
      nrm = fmaf(v.z, v.z, nrm); nrm = fmaf(v.w, v.w, nrm);
      ushort4 o; o.x = f2b(v.x); o.y = f2b(v.y); o.z = f2b(v.z); o.w = f2b(v.w);
      *(ushort4*)(dst + f * 4) = o;
    }
  }
  for (int off = 1; off <= 8; off <<= 1) nrm += __shfl_xor(nrm, off, 64);
  if (l == 0) bnorm[c * 128 + r] = nrm;
  if (l < 12) *(ushort4*)(dst + 784 + l * 4) = make_ushort4(0, 0, 0, 0);  // 784..831
}

// ---------------------------------------------------------------------------
// K3: fused MFMA GEMM-dist. grid 256 (one block per c), 512 threads (8 waves).
// Stage xre[c] (At) and ccb[c] (Bt) k-tiles ONCE; compute
//   D_x = A.B^T (dist + in-register softmax)  and  D_c = B.B^T.
// Wave w owns rows w*16..+15 of both outputs. The D_c A-operand is read from
// LDS at the wave-static row w*16+ln (NO dynamic register-array indexing —
// bf[w] in round 7 forced the whole fragment array to scratch: VALUBusy 70%,
// MfmaUtil 2%). All LDS offsets precomputed; j-loop fully unrolled.
// Double-buffered, issue-after-barrier. XOR chunk swizzle as before.
// ---------------------------------------------------------------------------
__global__ __launch_bounds__(512) void gemm_fused_kernel(
    const ushort* __restrict__ xre, const ushort* __restrict__ ccb,
    const float* __restrict__ anorm, const float* __restrict__ bnorm,
    float* __restrict__ out_d, float* __restrict__ out_s,
    float* __restrict__ out_c) {
  __shared__ __align__(16) ushort At[2][4096];  // 128 rows x 32 k
  __shared__ __align__(16) ushort Bt[2][4096];
  const int c = blockIdx.x;
  const int t = threadIdx.x, w = t >> 6, lane = t & 63;
  const int quad = lane >> 4, ln = lane & 15;
  const ushort* Ag = xre + (size_t)c * (128 * KPAD);
  const ushort* Bg = ccb + (size_t)c * (128 * KPAD);

  f32x4 accx[8], accc[8];
  for (int j = 0; j < 8; ++j) {
    accx[j] = f32x4{0.f, 0.f, 0.f, 0.f};
    accc[j] = f32x4{0.f, 0.f, 0.f, 0.f};
  }

  // staging: thread t covers chunk ci = t of the 128x32 tile
  // (row = ci>>2, stored chunk index q = (ci&3)^(row&3))
  const int srow = t >> 2, scq = (t & 3) ^ (srow & 3);
  const ushort* gA = Ag + (size_t)srow * KPAD + scq * 8;
  const ushort* gB = Bg + (size_t)srow * KPAD + scq * 8;

  // LDS fragment offsets (ushort units), computed once
  const int m = w * 16 + ln;
  const int aoff = (m * 4 + (quad ^ (m & 3))) * 8;   // row m of At / Bt
  int boff[8];
#pragma unroll
  for (int j = 0; j < 8; ++j) {
    int n = j * 16 + ln;
    boff[j] = (n * 4 + (quad ^ (n & 3))) * 8;
  }

#define ISSUE(k, p)                                                            \
  do {                                                                         \
    int kb = (k) * 32;                                                         \
    __builtin_amdgcn_global_load_lds(                                          \
        (const __attribute__((address_space(1))) unsigned int*)(gA + kb),      \
        (__attribute__((address_space(3))) unsigned int*)&At[p][t * 8], 16, 0, 0); \
    __builtin_amdgcn_global_load_lds(                                          \
        (const __attribute__((address_space(1))) unsigned int*)(gB + kb),      \
        (__attribute__((address_space(3))) unsigned int*)&Bt[p][t * 8], 16, 0, 0); \
  } while (0)

  ISSUE(0, 0);
  for (int k0 = 0; k0 < KTILES; ++k0) {
    __syncthreads();
    if (k0 < KTILES - 1) ISSUE(k0 + 1, (k0 + 1) & 1);
    const int p = k0 & 1;
    bf16x8 af = *(const bf16x8*)&At[p][aoff];   // x_re row m
    bf16x8 ar = *(const bf16x8*)&Bt[p][aoff];   // cc row m (same offset formula)
#pragma unroll
    for (int j = 0; j < 8; ++j) {
      bf16x8 bfj = *(const bf16x8*)&Bt[p][boff[j]];
      accx[j] = __builtin_amdgcn_mfma_f32_16x16x32_bf16(af, bfj, accx[j], 0, 0, 0);
      accc[j] = __builtin_amdgcn_mfma_f32_16x16x32_bf16(ar, bfj, accc[j], 0, 0, 0);
    }
  }
#undef ISSUE

  const float* an = anorm + c * 128;
  const float* bn = bnorm + c * 128;
  float cn[8];
  for (int j = 0; j < 8; ++j) cn[j] = bn[j * 16 + ln];
  float rx[4], rc[4];
  for (int r = 0; r < 4; ++r) {
    int mr = w * 16 + quad * 4 + r;
    rx[r] = an[mr];
    rc[r] = bn[mr];
  }
  // cluster_dist
  for (int r = 0; r < 4; ++r) {
    int mr = w * 16 + quad * 4 + r;
    float* ob = out_c + (size_t)c * (128 * 128) + (size_t)mr * 128;
    for (int j = 0; j < 8; ++j) {
      float d2 = rc[r] + cn[j] - 2.f * accc[j][r];
      ob[j * 16 + ln] = sqrtf(fmaxf(d2, 1e-12f));
    }
  }
  // x_distance + softmax (row fully in-quad: 8 regs x 16 ln)
  for (int r = 0; r < 4; ++r) {
    int mr = w * 16 + quad * 4 + r;
    float dr[8];
    for (int j = 0; j < 8; ++j) {
      float d2 = rx[r] + cn[j] - 2.f * accx[j][r];
      dr[j] = sqrtf(fmaxf(d2, 1e-12f));
    }
    float* ob = out_d + ((size_t)mr * 256 + c) * 128;
    for (int j = 0; j < 8; ++j) ob[j * 16 + ln] = dr[j];
    float mn = dr[0];
    for (int j = 1; j < 8; ++j) mn = fminf(mn, dr[j]);
    for (int off = 1; off <= 8; off <<= 1) mn = fminf(mn, __shfl_xor(mn, off, 64));
    float e[8], s = 0.f;
    for (int j = 0; j < 8; ++j) { e[j] = __expf(-32.f * (dr[j] - mn)); s += e[j]; }
    for (int off = 1; off <= 8; off <<= 1) s += __shfl_xor(s, off, 64);
    float inv = 1.f / s;
    float* os = out_s + ((size_t)mr * 256 + c) * 128;
    for (int j = 0; j < 8; ++j) os[j * 16 + ln] = e[j] * inv;
  }
}

extern "C" void kernel_launch(void* const* d_in, const int* in_sizes, int n_in,
                              void* d_out, int out_size, void* d_ws, size_t ws_size,
                              hipStream_t stream) {
  const float* x   = (const float*)d_in[0];
  const float* lnw = (const float*)d_in[1];
  const float* lnb = (const float*)d_in[2];
  const float* cc  = (const float*)d_in[3];
  float* out   = (float*)d_out;
  float* out_d = out;             // x_distance        [8,16,256,128]
  float* out_s = out + 4194304;   // x_distance_assign [8,16,256,128]
  float* out_c = out + 8388608;   // cluster_dist      [256,128,128]

  ushort* xre_b = (ushort*)d_ws;              // 256*128*832 bf16 = 54.5 MB
  ushort* cc_b  = xre_b + 27262976;           // 54.5 MB
  float*  anorm = (float*)(cc_b + 27262976);  // 256*128 fp32
  float*  bnorm = anorm + 32768;

  hipMemsetAsync(anorm, 0, 32768 * sizeof(float), stream);
  ln_transpose_kernel<<<dim3(13, 128), 256, 0, stream>>>(x, lnw, lnb, xre_b, anorm);
  cc_convert_kernel<<<2048, 256, 0, stream>>>(cc, cc_b, bnorm);
  gemm_fused_kernel<<<256, 512, 0, stream>>>(xre_b, cc_b, anorm, bnorm,
                                             out_d, out_s, out_c);
}